// Round 4
// baseline (288.708 us; speedup 1.0000x reference)
//
#include <hip/hip_runtime.h>
#include <hip/hip_bf16.h>
#include <math.h>

#define N_NODES 50000
#define N_EDGES 600000
#define DIM 128
#define KGAM 8
#define EPSV 1e-9f

typedef __attribute__((ext_vector_type(8))) short short8;
typedef __attribute__((ext_vector_type(4))) float float4v;

__device__ __forceinline__ float bf2f(short s) {
    unsigned int u = ((unsigned int)(unsigned short)s) << 16;
    return __builtin_bit_cast(float, u);
}
__device__ __forceinline__ short f2bf(float f) {
    return (short)__builtin_bit_cast(unsigned short, __float2bfloat16(f));
}
__device__ __forceinline__ unsigned int pack2(float a, float b) {
    return (unsigned int)(unsigned short)f2bf(a) | ((unsigned int)(unsigned short)f2bf(b) << 16);
}
__device__ __forceinline__ float sigm(float x) { return 1.f / (1.f + __expf(-x)); }

// ---------------- CSR build ----------------
__global__ void k_zero_int(int* __restrict__ p, int n) {
    int i = blockIdx.x * blockDim.x + threadIdx.x;
    if (i < n) p[i] = 0;
}

__global__ void k_deg(const int* __restrict__ dst, int* __restrict__ deg) {
    int e = blockIdx.x * blockDim.x + threadIdx.x;
    if (e < N_EDGES) atomicAdd(&deg[dst[e]], 1);
}

__global__ void k_scan1(const int* __restrict__ deg, int* __restrict__ rowstart,
                        int* __restrict__ bsums, float* __restrict__ norm) {
    __shared__ int s[256];
    int tid = threadIdx.x;
    int i0 = blockIdx.x * 1024 + tid * 4;
    int v[4]; int sum = 0;
#pragma unroll
    for (int c = 0; c < 4; ++c) {
        int i = i0 + c;
        int d = (i < N_NODES) ? deg[i] : 0;
        v[c] = d; sum += d;
    }
    s[tid] = sum; __syncthreads();
#pragma unroll
    for (int off = 1; off < 256; off <<= 1) {
        int t = (tid >= off) ? s[tid - off] : 0;
        __syncthreads();
        s[tid] += t;
        __syncthreads();
    }
    if (tid == 255) bsums[blockIdx.x] = s[255];
    int run = s[tid] - sum;
#pragma unroll
    for (int c = 0; c < 4; ++c) {
        int i = i0 + c;
        if (i < N_NODES) {
            rowstart[i] = run;
            norm[i] = rsqrtf((float)(v[c] < 1 ? 1 : v[c]));
        }
        run += v[c];
    }
}

__global__ void k_scan2(int* __restrict__ bsums, int nb) {
    __shared__ int s[64];
    int tid = threadIdx.x;
    int v = (tid < nb) ? bsums[tid] : 0;
    s[tid] = v; __syncthreads();
#pragma unroll
    for (int off = 1; off < 64; off <<= 1) {
        int t = (tid >= off) ? s[tid - off] : 0;
        __syncthreads();
        s[tid] += t;
        __syncthreads();
    }
    if (tid < nb) bsums[tid] = s[tid] - v;
}

__global__ void k_scan3(const int* __restrict__ bsums, int* __restrict__ rowstart) {
    int i = blockIdx.x * blockDim.x + threadIdx.x;
    if (i < N_NODES) rowstart[i] += bsums[i >> 10];
    if (i == 0) rowstart[N_NODES] = N_EDGES;
}

__global__ void k_fill(const int* __restrict__ src, const int* __restrict__ dst,
                       const int* __restrict__ rowstart, int* __restrict__ cnt,
                       int* __restrict__ esrc) {
    int e = blockIdx.x * blockDim.x + threadIdx.x;
    if (e < N_EDGES) {
        int d = dst[e];
        int slot = rowstart[d] + atomicAdd(&cnt[d], 1);
        esrc[slot] = src[e];
    }
}

// ---------------- blend coefficients ----------------
__global__ void k_coeffs(const float* __restrict__ gl, const float* __restrict__ gh,
                         const float* __restrict__ gm, float* __restrict__ c) {
    if (threadIdx.x == 0 && blockIdx.x == 0) {
        float a0 = 0, b0 = 0, a1 = 0, b1 = 0, sg = 0, m2 = 0;
        for (int k = 0; k < KGAM; ++k) {
            float al = EPSV + (float)k * (1.f - 2.f * EPSV) / (KGAM - 1);
            float md = EPSV + (float)k * (1.f - EPSV) / (KGAM - 1);
            float l = fmaxf(gl[k], 0.f), h = fmaxf(gh[k], 0.f), m = fmaxf(gm[k], 0.f);
            a0 += al * l;  b0 += (1.f - al) * l;
            a1 += -al * h; b1 += (1.f - al) * h;
            sg += m;       m2 += md * m;
        }
        c[0] = a0; c[1] = b0; c[2] = a1; c[3] = b1; c[4] = sg; c[5] = -m2;
    }
}

// ------------- weights: 6 coefficient-folded bf16 matrices -------------
// Wb[g] = c[g] * Wsrc(g), g: 0,1->W_low  2,3->W_high  4,5->W_mid
__global__ void k_wconv(const float* __restrict__ W0, const float* __restrict__ W1,
                        const float* __restrict__ W2, const float* __restrict__ coeffs,
                        unsigned int* __restrict__ Wb) {
    int g = blockIdx.y;
    const float* Ws = (g < 2) ? W0 : (g < 4) ? W1 : W2;
    float c = coeffs[g];
    int i = (blockIdx.x * 256 + threadIdx.x) * 4;
    if (i < DIM * DIM) {
        float4 v = *(const float4*)(Ws + i);
        uint2 o; o.x = pack2(c * v.x, c * v.y); o.y = pack2(c * v.z, c * v.w);
        *(uint2*)(Wb + (g * DIM * DIM + i) / 2) = o;
    }
}

// ---------------- prescale: fb = bf16(feature), fp = bf16(feature*norm) ----------
__global__ void k_prescale(const float4* __restrict__ f, const float* __restrict__ norm,
                           uint2* __restrict__ fb, uint2* __restrict__ fp) {
    int i = blockIdx.x * 256 + threadIdx.x;
    if (i >= N_NODES * DIM / 4) return;
    int row = i >> 5;
    float nv = norm[row];
    float4 v = f[i];
    uint2 a; a.x = pack2(v.x, v.y); a.y = pack2(v.z, v.w);
    uint2 b; b.x = pack2(v.x * nv, v.y * nv); b.y = pack2(v.z * nv, v.w * nv);
    fb[i] = a;
    fp[i] = b;
}

// ---------------- SpMM: 4 nodes/wave (16 lanes x 8 bf16), unroll-4 ----------------
__device__ __forceinline__ void acc8(float* a, uint4 r) {
    a[0] += __builtin_bit_cast(float, r.x << 16);
    a[1] += __builtin_bit_cast(float, r.x & 0xffff0000u);
    a[2] += __builtin_bit_cast(float, r.y << 16);
    a[3] += __builtin_bit_cast(float, r.y & 0xffff0000u);
    a[4] += __builtin_bit_cast(float, r.z << 16);
    a[5] += __builtin_bit_cast(float, r.z & 0xffff0000u);
    a[6] += __builtin_bit_cast(float, r.w << 16);
    a[7] += __builtin_bit_cast(float, r.w & 0xffff0000u);
}

__global__ void k_spmm(const uint4* __restrict__ in, const float* __restrict__ norm,
                       const int* __restrict__ rowstart, const int* __restrict__ esrc,
                       uint4* __restrict__ hout, uint4* __restrict__ preout, int wpre) {
    int v = blockIdx.x * 16 + (threadIdx.x >> 4);
    int l = threadIdx.x & 15;
    if (v >= N_NODES) return;
    int beg = rowstart[v], end = rowstart[v + 1];
    float a[8] = {0.f, 0.f, 0.f, 0.f, 0.f, 0.f, 0.f, 0.f};
    int t = beg;
    for (; t + 3 < end; t += 4) {
        int u0 = esrc[t], u1 = esrc[t + 1], u2 = esrc[t + 2], u3 = esrc[t + 3];
        uint4 r0 = in[(size_t)u0 * 16 + l];
        uint4 r1 = in[(size_t)u1 * 16 + l];
        uint4 r2 = in[(size_t)u2 * 16 + l];
        uint4 r3 = in[(size_t)u3 * 16 + l];
        acc8(a, r0); acc8(a, r1); acc8(a, r2); acc8(a, r3);
    }
    for (; t < end; ++t) {
        uint4 r = in[(size_t)esrc[t] * 16 + l];
        acc8(a, r);
    }
    float nv = norm[v];
    uint4 o;
    o.x = pack2(a[0] * nv, a[1] * nv); o.y = pack2(a[2] * nv, a[3] * nv);
    o.z = pack2(a[4] * nv, a[5] * nv); o.w = pack2(a[6] * nv, a[7] * nv);
    hout[(size_t)v * 16 + l] = o;
    if (wpre) {
        float n2 = nv * nv;
        uint4 p;
        p.x = pack2(a[0] * n2, a[1] * n2); p.y = pack2(a[2] * n2, a[3] * n2);
        p.z = pack2(a[4] * n2, a[5] * n2); p.w = pack2(a[6] * n2, a[7] * n2);
        preout[(size_t)v * 16 + l] = p;
    }
}

// ------- fused tri-GEMM, LDS-free: A-frags straight from global, folded weights ----
// A: lane holds A[m=lane&15][k=quad*8+j]; B: lane holds W[n=lane&15][k=quad*8+j];
// C/D: col=lane&15, row=quad*4+reg  (mapping verified by R2/R3 passes)
#define RT 64

__global__ __launch_bounds__(512, 4) void k_gemm_fused(
    const short* __restrict__ hB, const short* __restrict__ fB,
    const short* __restrict__ h1B, const short* __restrict__ Wb,
    const float* __restrict__ bias, const float* __restrict__ snorm,
    float* __restrict__ out) {
    const int r0 = blockIdx.x * RT;
    const int tid = threadIdx.x;
    const int lane = tid & 63;
    const int ct = tid >> 6;        // wave owns one 16-col output tile
    const int m = lane & 15;
    const int quad = lane >> 4;

    float4v acc[3][4];
    const float4v zero = {0.f, 0.f, 0.f, 0.f};
#pragma unroll
    for (int g = 0; g < 3; ++g)
#pragma unroll
        for (int rt = 0; rt < 4; ++rt) acc[g][rt] = zero;

    // per-lane base pointers (row m of the 16-row sub-tiles; quad picks k-octet)
    const short* ah = hB  + (size_t)(r0 + m) * DIM + quad * 8;
    const short* af = fB  + (size_t)(r0 + m) * DIM + quad * 8;
    const short* a1 = h1B + (size_t)(r0 + m) * DIM + quad * 8;
    const short* wp = Wb  + (size_t)(ct * 16 + m) * DIM + quad * 8;

#pragma unroll
    for (int ks = 0; ks < 4; ++ks) {
        const int ko = ks * 32;
        short8 b0 = *(const short8*)(wp + ko);
        short8 b1 = *(const short8*)(wp + ko + DIM * DIM);
        short8 b2 = *(const short8*)(wp + ko + 2 * DIM * DIM);
        short8 b3 = *(const short8*)(wp + ko + 3 * DIM * DIM);
        short8 b4 = *(const short8*)(wp + ko + 4 * DIM * DIM);
        short8 b5 = *(const short8*)(wp + ko + 5 * DIM * DIM);
#pragma unroll
        for (int rt = 0; rt < 4; ++rt) {
            const int ro = rt * 16 * DIM + ko;
            short8 x_h = *(const short8*)(ah + ro);
            short8 x_f = *(const short8*)(af + ro);
            short8 x_1 = *(const short8*)(a1 + ro);
            acc[0][rt] = __builtin_amdgcn_mfma_f32_16x16x32_bf16(x_h, b0, acc[0][rt], 0, 0, 0);
            acc[0][rt] = __builtin_amdgcn_mfma_f32_16x16x32_bf16(x_f, b1, acc[0][rt], 0, 0, 0);
            acc[1][rt] = __builtin_amdgcn_mfma_f32_16x16x32_bf16(x_h, b2, acc[1][rt], 0, 0, 0);
            acc[1][rt] = __builtin_amdgcn_mfma_f32_16x16x32_bf16(x_f, b3, acc[1][rt], 0, 0, 0);
            acc[2][rt] = __builtin_amdgcn_mfma_f32_16x16x32_bf16(x_1, b4, acc[2][rt], 0, 0, 0);
            acc[2][rt] = __builtin_amdgcn_mfma_f32_16x16x32_bf16(x_f, b5, acc[2][rt], 0, 0, 0);
        }
    }

    // epilogue: sequential mutual gating + bias + graph-norm + relu
    const int col = ct * 16 + m;
    const float bc = bias[col];
#pragma unroll
    for (int rt = 0; rt < 4; ++rt) {
#pragma unroll
        for (int r = 0; r < 4; ++r) {
            int row = r0 + rt * 16 + quad * 4 + r;
            if (row < N_NODES) {
                float sn = snorm[row];
                float o0 = acc[0][rt][r], o1 = acc[1][rt][r], o2 = acc[2][rt][r];
                float g0 = o0 * sigm(o1 + o2);
                float g1 = o1 * sigm(g0 + o2);
                float g2 = o2 * sigm(g0 + g1);
                float vv = (g0 + g1 + g2 + bc) * sn;
                out[(size_t)row * DIM + col] = fmaxf(vv, 0.f);
            }
        }
    }
}

extern "C" void kernel_launch(void* const* d_in, const int* in_sizes, int n_in,
                              void* d_out, int out_size, void* d_ws, size_t ws_size,
                              hipStream_t stream) {
    const float* feature = (const float*)d_in[0];
    const float* snorm   = (const float*)d_in[1];
    const int*   src     = (const int*)d_in[2];
    const int*   dst     = (const int*)d_in[3];
    const float* W_low   = (const float*)d_in[4];
    const float* W_high  = (const float*)d_in[5];
    const float* W_mid   = (const float*)d_in[6];
    const float* gl      = (const float*)d_in[7];
    const float* gh      = (const float*)d_in[8];
    const float* gm      = (const float*)d_in[9];
    const float* bias    = (const float*)d_in[10];
    float* out = (float*)d_out;

    char* w = (char*)d_ws;
    auto alloc = [&](size_t bytes) {
        char* p = w;
        w += (bytes + 255) & ~(size_t)255;
        return p;
    };
    float* norm   = (float*)alloc((size_t)N_NODES * 4);
    int* deg      = (int*)alloc((size_t)2 * N_NODES * 4);
    int* cnt      = deg + N_NODES;
    int* rowstart = (int*)alloc((size_t)(N_NODES + 1) * 4);
    int* bsums    = (int*)alloc(64 * 4);
    int* esrc     = (int*)alloc((size_t)N_EDGES * 4);
    float* coeffs = (float*)alloc(64 * 4);
    short* Wb     = (short*)alloc((size_t)6 * DIM * DIM * 2);
    short* fb     = (short*)alloc((size_t)N_NODES * DIM * 2);
    short* fp     = (short*)alloc((size_t)N_NODES * DIM * 2);
    short* h      = (short*)alloc((size_t)N_NODES * DIM * 2);
    short* hp     = (short*)alloc((size_t)N_NODES * DIM * 2);
    short* h1     = (short*)alloc((size_t)N_NODES * DIM * 2);

    k_zero_int<<<(2 * N_NODES + 255) / 256, 256, 0, stream>>>(deg, 2 * N_NODES);
    k_deg<<<(N_EDGES + 255) / 256, 256, 0, stream>>>(dst, deg);
    int nchunks = (N_NODES + 1023) / 1024;  // 49
    k_scan1<<<nchunks, 256, 0, stream>>>(deg, rowstart, bsums, norm);
    k_scan2<<<1, 64, 0, stream>>>(bsums, nchunks);
    k_scan3<<<(N_NODES + 255) / 256, 256, 0, stream>>>(bsums, rowstart);
    k_fill<<<(N_EDGES + 255) / 256, 256, 0, stream>>>(src, dst, rowstart, cnt, esrc);
    k_coeffs<<<1, 1, 0, stream>>>(gl, gh, gm, coeffs);
    k_wconv<<<dim3(16, 6), 256, 0, stream>>>(W_low, W_high, W_mid, coeffs,
                                             (unsigned int*)Wb);
    k_prescale<<<(N_NODES * DIM / 4 + 255) / 256, 256, 0, stream>>>(
        (const float4*)feature, norm, (uint2*)fb, (uint2*)fp);

    int spmm_blocks = (N_NODES + 15) / 16;
    k_spmm<<<spmm_blocks, 256, 0, stream>>>((const uint4*)fp, norm, rowstart, esrc,
                                            (uint4*)h, (uint4*)hp, 1);
    k_spmm<<<spmm_blocks, 256, 0, stream>>>((const uint4*)hp, norm, rowstart, esrc,
                                            (uint4*)h1, (uint4*)hp, 0);

    k_gemm_fused<<<(N_NODES + RT - 1) / RT, 512, 0, stream>>>(
        h, fb, h1, Wb, bias, snorm, out);
}

// Round 5
// 256.519 us; speedup vs baseline: 1.1255x; 1.1255x over previous
//
#include <hip/hip_runtime.h>
#include <hip/hip_bf16.h>
#include <math.h>

#define N_NODES 50000
#define N_EDGES 600000
#define DIM 128
#define KGAM 8
#define EPSV 1e-9f

typedef __attribute__((ext_vector_type(8))) short short8;
typedef __attribute__((ext_vector_type(4))) float float4v;

__device__ __forceinline__ short f2bf(float f) {
    return (short)__builtin_bit_cast(unsigned short, __float2bfloat16(f));
}
__device__ __forceinline__ unsigned int pack2(float a, float b) {
    return (unsigned int)(unsigned short)f2bf(a) | ((unsigned int)(unsigned short)f2bf(b) << 16);
}
__device__ __forceinline__ float sigm(float x) { return 1.f / (1.f + __expf(-x)); }

// ---------------- CSR build ----------------
__global__ void k_deg(const int* __restrict__ dst, int* __restrict__ deg) {
    int e = blockIdx.x * blockDim.x + threadIdx.x;
    if (e < N_EDGES) atomicAdd(&deg[dst[e]], 1);
}

__global__ void k_scan1(const int* __restrict__ deg, int* __restrict__ rowstart,
                        int* __restrict__ bsums, float* __restrict__ norm) {
    __shared__ int s[256];
    int tid = threadIdx.x;
    int i0 = blockIdx.x * 1024 + tid * 4;
    int v[4]; int sum = 0;
#pragma unroll
    for (int c = 0; c < 4; ++c) {
        int i = i0 + c;
        int d = (i < N_NODES) ? deg[i] : 0;
        v[c] = d; sum += d;
    }
    s[tid] = sum; __syncthreads();
#pragma unroll
    for (int off = 1; off < 256; off <<= 1) {
        int t = (tid >= off) ? s[tid - off] : 0;
        __syncthreads();
        s[tid] += t;
        __syncthreads();
    }
    if (tid == 255) bsums[blockIdx.x] = s[255];
    int run = s[tid] - sum;
#pragma unroll
    for (int c = 0; c < 4; ++c) {
        int i = i0 + c;
        if (i < N_NODES) {
            rowstart[i] = run;
            norm[i] = rsqrtf((float)(v[c] < 1 ? 1 : v[c]));
        }
        run += v[c];
    }
}

__global__ void k_scan2(int* __restrict__ bsums, int nb) {
    __shared__ int s[64];
    int tid = threadIdx.x;
    int v = (tid < nb) ? bsums[tid] : 0;
    s[tid] = v; __syncthreads();
#pragma unroll
    for (int off = 1; off < 64; off <<= 1) {
        int t = (tid >= off) ? s[tid - off] : 0;
        __syncthreads();
        s[tid] += t;
        __syncthreads();
    }
    if (tid < nb) bsums[tid] = s[tid] - v;
}

__global__ void k_scan3(const int* __restrict__ bsums, int* __restrict__ rowstart) {
    int i = blockIdx.x * blockDim.x + threadIdx.x;
    if (i < N_NODES) rowstart[i] += bsums[i >> 10];
    if (i == 0) rowstart[N_NODES] = N_EDGES;
}

__global__ void k_fill(const int* __restrict__ src, const int* __restrict__ dst,
                       const int* __restrict__ rowstart, int* __restrict__ cnt,
                       int* __restrict__ esrc) {
    int e = blockIdx.x * blockDim.x + threadIdx.x;
    if (e < N_EDGES) {
        int d = dst[e];
        int slot = rowstart[d] + atomicAdd(&cnt[d], 1);
        esrc[slot] = src[e];
    }
}

// ------------- weights: 6 coefficient-folded bf16 matrices (coeffs inlined) -------
// g: 0,1 -> W_low ; 2,3 -> W_high ; 4,5 -> W_mid
__global__ void k_wconv(const float* __restrict__ W0, const float* __restrict__ W1,
                        const float* __restrict__ W2, const float* __restrict__ gl,
                        const float* __restrict__ gh, const float* __restrict__ gm,
                        unsigned int* __restrict__ Wb) {
    int g = blockIdx.y;
    float a0 = 0, b0 = 0, a1 = 0, b1 = 0, sg = 0, m2 = 0;
#pragma unroll
    for (int k = 0; k < KGAM; ++k) {
        float al = EPSV + (float)k * (1.f - 2.f * EPSV) / (KGAM - 1);
        float md = EPSV + (float)k * (1.f - EPSV) / (KGAM - 1);
        float l = fmaxf(gl[k], 0.f), h = fmaxf(gh[k], 0.f), m = fmaxf(gm[k], 0.f);
        a0 += al * l;  b0 += (1.f - al) * l;
        a1 += -al * h; b1 += (1.f - al) * h;
        sg += m;       m2 += md * m;
    }
    float cc[6] = {a0, b0, a1, b1, sg, -m2};
    float c = cc[g];
    const float* Ws = (g < 2) ? W0 : (g < 4) ? W1 : W2;
    int i = (blockIdx.x * 256 + threadIdx.x) * 4;
    if (i < DIM * DIM) {
        float4 v = *(const float4*)(Ws + i);
        uint2 o; o.x = pack2(c * v.x, c * v.y); o.y = pack2(c * v.z, c * v.w);
        *(uint2*)(Wb + (g * DIM * DIM + i) / 2) = o;
    }
}

// ---------------- prescale: fb = bf16(feature), fp = bf16(feature*norm) ----------
__global__ void k_prescale(const float4* __restrict__ f, const float* __restrict__ norm,
                           uint2* __restrict__ fb, uint2* __restrict__ fp) {
    int i = blockIdx.x * 256 + threadIdx.x;
    if (i >= N_NODES * DIM / 4) return;
    int row = i >> 5;
    float nv = norm[row];
    float4 v = f[i];
    uint2 a; a.x = pack2(v.x, v.y); a.y = pack2(v.z, v.w);
    uint2 b; b.x = pack2(v.x * nv, v.y * nv); b.y = pack2(v.z * nv, v.w * nv);
    fb[i] = a;
    fp[i] = b;
}

// ---------------- SpMM: 4 nodes/wave (16 lanes x 8 bf16), 8/4/2/1 ladder ----------
__device__ __forceinline__ void acc8(float* a, uint4 r) {
    a[0] += __builtin_bit_cast(float, r.x << 16);
    a[1] += __builtin_bit_cast(float, r.x & 0xffff0000u);
    a[2] += __builtin_bit_cast(float, r.y << 16);
    a[3] += __builtin_bit_cast(float, r.y & 0xffff0000u);
    a[4] += __builtin_bit_cast(float, r.z << 16);
    a[5] += __builtin_bit_cast(float, r.z & 0xffff0000u);
    a[6] += __builtin_bit_cast(float, r.w << 16);
    a[7] += __builtin_bit_cast(float, r.w & 0xffff0000u);
}

__global__ void k_spmm(const uint4* __restrict__ in, const float* __restrict__ norm,
                       const int* __restrict__ rowstart, const int* __restrict__ esrc,
                       uint4* __restrict__ hout, uint4* __restrict__ preout, int wpre) {
    int v = blockIdx.x * 16 + (threadIdx.x >> 4);
    int l = threadIdx.x & 15;
    if (v >= N_NODES) return;
    int beg = rowstart[v], end = rowstart[v + 1];
    float a[8] = {0.f, 0.f, 0.f, 0.f, 0.f, 0.f, 0.f, 0.f};
    int t = beg;
    for (; t + 7 < end; t += 8) {
        int u0 = esrc[t],     u1 = esrc[t + 1], u2 = esrc[t + 2], u3 = esrc[t + 3];
        int u4 = esrc[t + 4], u5 = esrc[t + 5], u6 = esrc[t + 6], u7 = esrc[t + 7];
        uint4 r0 = in[(size_t)u0 * 16 + l];
        uint4 r1 = in[(size_t)u1 * 16 + l];
        uint4 r2 = in[(size_t)u2 * 16 + l];
        uint4 r3 = in[(size_t)u3 * 16 + l];
        uint4 r4 = in[(size_t)u4 * 16 + l];
        uint4 r5 = in[(size_t)u5 * 16 + l];
        uint4 r6 = in[(size_t)u6 * 16 + l];
        uint4 r7 = in[(size_t)u7 * 16 + l];
        acc8(a, r0); acc8(a, r1); acc8(a, r2); acc8(a, r3);
        acc8(a, r4); acc8(a, r5); acc8(a, r6); acc8(a, r7);
    }
    if (t + 3 < end) {
        int u0 = esrc[t], u1 = esrc[t + 1], u2 = esrc[t + 2], u3 = esrc[t + 3];
        uint4 r0 = in[(size_t)u0 * 16 + l];
        uint4 r1 = in[(size_t)u1 * 16 + l];
        uint4 r2 = in[(size_t)u2 * 16 + l];
        uint4 r3 = in[(size_t)u3 * 16 + l];
        acc8(a, r0); acc8(a, r1); acc8(a, r2); acc8(a, r3);
        t += 4;
    }
    if (t + 1 < end) {
        int u0 = esrc[t], u1 = esrc[t + 1];
        uint4 r0 = in[(size_t)u0 * 16 + l];
        uint4 r1 = in[(size_t)u1 * 16 + l];
        acc8(a, r0); acc8(a, r1);
        t += 2;
    }
    if (t < end) {
        uint4 r = in[(size_t)esrc[t] * 16 + l];
        acc8(a, r);
    }
    float nv = norm[v];
    uint4 o;
    o.x = pack2(a[0] * nv, a[1] * nv); o.y = pack2(a[2] * nv, a[3] * nv);
    o.z = pack2(a[4] * nv, a[5] * nv); o.w = pack2(a[6] * nv, a[7] * nv);
    hout[(size_t)v * 16 + l] = o;
    if (wpre) {
        float n2 = nv * nv;
        uint4 p;
        p.x = pack2(a[0] * n2, a[1] * n2); p.y = pack2(a[2] * n2, a[3] * n2);
        p.z = pack2(a[4] * n2, a[5] * n2); p.w = pack2(a[6] * n2, a[7] * n2);
        preout[(size_t)v * 16 + l] = p;
    }
}

// ------- fused tri-GEMM: global_load_lds stages A in MFMA-fragment order ----------
// 48 slices of 1KB: slice s = g*16 + rt*4 + ks. DMA lane l writes LDS base+l*16 and
// gathers global row (r0+rt*16+(l&15)), cols ks*32+(l>>4)*8 — exactly the fragment
// that reading lane l needs. ds_read_b128 is then stride-1 (conflict-free).
// A: lane holds A[m=lane&15][k=quad*8+j]; B: lane holds W[n=lane&15][k=quad*8+j];
// C/D: col=lane&15, row=quad*4+reg  (verified R2-R4 passes)
#define RT 64

typedef const __attribute__((address_space(1))) unsigned int* gp1_t;
typedef __attribute__((address_space(3))) unsigned int* lp3_t;

__global__ __launch_bounds__(512, 4) void k_gemm_fused(
    const short* __restrict__ hB, const short* __restrict__ fB,
    const short* __restrict__ h1B, const short* __restrict__ Wb,
    const float* __restrict__ bias, const float* __restrict__ snorm,
    float* __restrict__ out) {
    __shared__ short Ts[48 * 512];   // 48 KB

    const int r0 = blockIdx.x * RT;
    const int tid = threadIdx.x;
    const int lane = tid & 63;
    const int wv = tid >> 6;         // 0..7: wave owns one 16-col output tile
    const int m = lane & 15;
    const int quad = lane >> 4;

    // stage A tiles: wave wv issues slices wv*6 .. wv*6+5
#pragma unroll
    for (int i = 0; i < 6; ++i) {
        int s = wv * 6 + i;
        int g = s >> 4, rt = (s >> 2) & 3, ks = s & 3;
        const short* base = (g == 0) ? hB : (g == 1) ? fB : h1B;
        int row = r0 + rt * 16 + m;
        row = (row < N_NODES) ? row : (N_NODES - 1);   // clamped rows never stored
        const short* gp = base + (size_t)row * DIM + ks * 32 + quad * 8;
        __builtin_amdgcn_global_load_lds((gp1_t)(const void*)gp,
                                         (lp3_t)(void*)&Ts[s * 512], 16, 0, 0);
    }
    __syncthreads();

    float4v acc[3][4];
    const float4v zero = {0.f, 0.f, 0.f, 0.f};
#pragma unroll
    for (int g = 0; g < 3; ++g)
#pragma unroll
        for (int rt = 0; rt < 4; ++rt) acc[g][rt] = zero;

    const short* wp = Wb + (size_t)(wv * 16 + m) * DIM + quad * 8;
#pragma unroll
    for (int ks = 0; ks < 4; ++ks) {
        const int ko = ks * 32;
        short8 b0 = *(const short8*)(wp + ko);
        short8 b1 = *(const short8*)(wp + ko + DIM * DIM);
        short8 b2 = *(const short8*)(wp + ko + 2 * DIM * DIM);
        short8 b3 = *(const short8*)(wp + ko + 3 * DIM * DIM);
        short8 b4 = *(const short8*)(wp + ko + 4 * DIM * DIM);
        short8 b5 = *(const short8*)(wp + ko + 5 * DIM * DIM);
#pragma unroll
        for (int rt = 0; rt < 4; ++rt) {
            const short* ap = &Ts[(rt * 4 + ks) * 512 + lane * 8];
            short8 x_h = *(const short8*)(ap);
            short8 x_f = *(const short8*)(ap + 16 * 512);
            short8 x_1 = *(const short8*)(ap + 32 * 512);
            acc[0][rt] = __builtin_amdgcn_mfma_f32_16x16x32_bf16(x_h, b0, acc[0][rt], 0, 0, 0);
            acc[0][rt] = __builtin_amdgcn_mfma_f32_16x16x32_bf16(x_f, b1, acc[0][rt], 0, 0, 0);
            acc[1][rt] = __builtin_amdgcn_mfma_f32_16x16x32_bf16(x_h, b2, acc[1][rt], 0, 0, 0);
            acc[1][rt] = __builtin_amdgcn_mfma_f32_16x16x32_bf16(x_f, b3, acc[1][rt], 0, 0, 0);
            acc[2][rt] = __builtin_amdgcn_mfma_f32_16x16x32_bf16(x_1, b4, acc[2][rt], 0, 0, 0);
            acc[2][rt] = __builtin_amdgcn_mfma_f32_16x16x32_bf16(x_f, b5, acc[2][rt], 0, 0, 0);
        }
    }

    // epilogue: sequential mutual gating + bias + graph-norm + relu
    const int col = wv * 16 + m;
    const float bc = bias[col];
#pragma unroll
    for (int rt = 0; rt < 4; ++rt) {
#pragma unroll
        for (int r = 0; r < 4; ++r) {
            int row = r0 + rt * 16 + quad * 4 + r;
            if (row < N_NODES) {
                float sn = snorm[row];
                float o0 = acc[0][rt][r], o1 = acc[1][rt][r], o2 = acc[2][rt][r];
                float g0 = o0 * sigm(o1 + o2);
                float g1 = o1 * sigm(g0 + o2);
                float g2 = o2 * sigm(g0 + g1);
                float vv = (g0 + g1 + g2 + bc) * sn;
                out[(size_t)row * DIM + col] = fmaxf(vv, 0.f);
            }
        }
    }
}

extern "C" void kernel_launch(void* const* d_in, const int* in_sizes, int n_in,
                              void* d_out, int out_size, void* d_ws, size_t ws_size,
                              hipStream_t stream) {
    const float* feature = (const float*)d_in[0];
    const float* snorm   = (const float*)d_in[1];
    const int*   src     = (const int*)d_in[2];
    const int*   dst     = (const int*)d_in[3];
    const float* W_low   = (const float*)d_in[4];
    const float* W_high  = (const float*)d_in[5];
    const float* W_mid   = (const float*)d_in[6];
    const float* gl      = (const float*)d_in[7];
    const float* gh      = (const float*)d_in[8];
    const float* gm      = (const float*)d_in[9];
    const float* bias    = (const float*)d_in[10];
    float* out = (float*)d_out;

    char* w = (char*)d_ws;
    auto alloc = [&](size_t bytes) {
        char* p = w;
        w += (bytes + 255) & ~(size_t)255;
        return p;
    };
    float* norm   = (float*)alloc((size_t)N_NODES * 4);
    int* deg      = (int*)alloc((size_t)2 * N_NODES * 4);
    int* cnt      = deg + N_NODES;
    int* rowstart = (int*)alloc((size_t)(N_NODES + 1) * 4);
    int* bsums    = (int*)alloc(64 * 4);
    int* esrc     = (int*)alloc((size_t)N_EDGES * 4);
    short* Wb     = (short*)alloc((size_t)6 * DIM * DIM * 2);
    short* fb     = (short*)alloc((size_t)N_NODES * DIM * 2);
    short* fp     = (short*)alloc((size_t)N_NODES * DIM * 2);
    short* h      = (short*)alloc((size_t)N_NODES * DIM * 2);
    short* hp     = (short*)alloc((size_t)N_NODES * DIM * 2);
    short* h1     = (short*)alloc((size_t)N_NODES * DIM * 2);

    hipMemsetAsync(deg, 0, (size_t)2 * N_NODES * 4, stream);
    k_deg<<<(N_EDGES + 255) / 256, 256, 0, stream>>>(dst, deg);
    int nchunks = (N_NODES + 1023) / 1024;  // 49
    k_scan1<<<nchunks, 256, 0, stream>>>(deg, rowstart, bsums, norm);
    k_scan2<<<1, 64, 0, stream>>>(bsums, nchunks);
    k_scan3<<<(N_NODES + 255) / 256, 256, 0, stream>>>(bsums, rowstart);
    k_fill<<<(N_EDGES + 255) / 256, 256, 0, stream>>>(src, dst, rowstart, cnt, esrc);
    k_wconv<<<dim3(16, 6), 256, 0, stream>>>(W_low, W_high, W_mid, gl, gh, gm,
                                             (unsigned int*)Wb);
    k_prescale<<<(N_NODES * DIM / 4 + 255) / 256, 256, 0, stream>>>(
        (const float4*)feature, norm, (uint2*)fb, (uint2*)fp);

    int spmm_blocks = (N_NODES + 15) / 16;
    k_spmm<<<spmm_blocks, 256, 0, stream>>>((const uint4*)fp, norm, rowstart, esrc,
                                            (uint4*)h, (uint4*)hp, 1);
    k_spmm<<<spmm_blocks, 256, 0, stream>>>((const uint4*)hp, norm, rowstart, esrc,
                                            (uint4*)h1, (uint4*)hp, 0);

    k_gemm_fused<<<(N_NODES + RT - 1) / RT, 512, 0, stream>>>(
        h, fb, h1, Wb, bias, snorm, out);
}

// Round 6
// 255.760 us; speedup vs baseline: 1.1288x; 1.0030x over previous
//
#include <hip/hip_runtime.h>
#include <hip/hip_bf16.h>
#include <math.h>

#define N_NODES 50000
#define N_EDGES 600000
#define DIM 128
#define KGAM 8
#define EPSV 1e-9f
#define RBLK 3128   // ceil(50048/16): padded row-blocks for tiled A arrays

typedef __attribute__((ext_vector_type(8))) short short8;
typedef __attribute__((ext_vector_type(4))) float float4v;

__device__ __forceinline__ short f2bf(float f) {
    return (short)__builtin_bit_cast(unsigned short, __float2bfloat16(f));
}
__device__ __forceinline__ unsigned int pack2(float a, float b) {
    return (unsigned int)(unsigned short)f2bf(a) | ((unsigned int)(unsigned short)f2bf(b) << 16);
}
__device__ __forceinline__ float sigm(float x) { return 1.f / (1.f + __expf(-x)); }

// ---------------- CSR build ----------------
__global__ void k_deg(const int* __restrict__ dst, int* __restrict__ deg) {
    int e = blockIdx.x * blockDim.x + threadIdx.x;
    if (e < N_EDGES) atomicAdd(&deg[dst[e]], 1);
}

__global__ void k_scan1(const int* __restrict__ deg, int* __restrict__ rowstart,
                        int* __restrict__ bsums, float* __restrict__ norm) {
    __shared__ int s[256];
    int tid = threadIdx.x;
    int i0 = blockIdx.x * 1024 + tid * 4;
    int v[4]; int sum = 0;
#pragma unroll
    for (int c = 0; c < 4; ++c) {
        int i = i0 + c;
        int d = (i < N_NODES) ? deg[i] : 0;
        v[c] = d; sum += d;
    }
    s[tid] = sum; __syncthreads();
#pragma unroll
    for (int off = 1; off < 256; off <<= 1) {
        int t = (tid >= off) ? s[tid - off] : 0;
        __syncthreads();
        s[tid] += t;
        __syncthreads();
    }
    if (tid == 255) bsums[blockIdx.x] = s[255];
    int run = s[tid] - sum;
#pragma unroll
    for (int c = 0; c < 4; ++c) {
        int i = i0 + c;
        if (i < N_NODES) {
            rowstart[i] = run;
            norm[i] = rsqrtf((float)(v[c] < 1 ? 1 : v[c]));
        }
        run += v[c];
    }
}

__global__ void k_scan2(int* __restrict__ bsums, int nb) {
    __shared__ int s[64];
    int tid = threadIdx.x;
    int v = (tid < nb) ? bsums[tid] : 0;
    s[tid] = v; __syncthreads();
#pragma unroll
    for (int off = 1; off < 64; off <<= 1) {
        int t = (tid >= off) ? s[tid - off] : 0;
        __syncthreads();
        s[tid] += t;
        __syncthreads();
    }
    if (tid < nb) bsums[tid] = s[tid] - v;
}

__global__ void k_scan3(const int* __restrict__ bsums, int* __restrict__ rowstart) {
    int i = blockIdx.x * blockDim.x + threadIdx.x;
    if (i < N_NODES) rowstart[i] += bsums[i >> 10];
    if (i == 0) rowstart[N_NODES] = N_EDGES;
}

__global__ void k_fill(const int* __restrict__ src, const int* __restrict__ dst,
                       const int* __restrict__ rowstart, int* __restrict__ cnt,
                       int* __restrict__ esrc) {
    int e = blockIdx.x * blockDim.x + threadIdx.x;
    if (e < N_EDGES) {
        int d = dst[e];
        int slot = rowstart[d] + atomicAdd(&cnt[d], 1);
        esrc[slot] = src[e];
    }
}

// ------------- weights: 6 coefficient-folded bf16 matrices (coeffs inlined) -------
__global__ void k_wconv(const float* __restrict__ W0, const float* __restrict__ W1,
                        const float* __restrict__ W2, const float* __restrict__ gl,
                        const float* __restrict__ gh, const float* __restrict__ gm,
                        unsigned int* __restrict__ Wb) {
    int g = blockIdx.y;
    float a0 = 0, b0 = 0, a1 = 0, b1 = 0, sg = 0, m2 = 0;
#pragma unroll
    for (int k = 0; k < KGAM; ++k) {
        float al = EPSV + (float)k * (1.f - 2.f * EPSV) / (KGAM - 1);
        float md = EPSV + (float)k * (1.f - EPSV) / (KGAM - 1);
        float l = fmaxf(gl[k], 0.f), h = fmaxf(gh[k], 0.f), m = fmaxf(gm[k], 0.f);
        a0 += al * l;  b0 += (1.f - al) * l;
        a1 += -al * h; b1 += (1.f - al) * h;
        sg += m;       m2 += md * m;
    }
    float cc[6] = {a0, b0, a1, b1, sg, -m2};
    float c = cc[g];
    const float* Ws = (g < 2) ? W0 : (g < 4) ? W1 : W2;
    int i = (blockIdx.x * 256 + threadIdx.x) * 4;
    if (i < DIM * DIM) {
        float4 v = *(const float4*)(Ws + i);
        uint2 o; o.x = pack2(c * v.x, c * v.y); o.y = pack2(c * v.z, c * v.w);
        *(uint2*)(Wb + (g * DIM * DIM + i) / 2) = o;
    }
}

// tiled A-layout short-offset for (row, k): fragment-major so the GEMM's
// global_load_lds staging is a contiguous 1KB per slice.
__device__ __forceinline__ size_t tiled_off(int row, int k) {
    return (size_t)(row >> 4) * 2048 + ((k >> 5) << 9) + (((k >> 3) & 3) << 7)
         + ((row & 15) << 3) + (k & 7);
}

// -------- prescale: fb = bf16(feature) [tiled], fp = bf16(feature*norm) [row-major]
__global__ void k_prescale(const float4* __restrict__ f, const float* __restrict__ norm,
                           unsigned int* __restrict__ fb, uint2* __restrict__ fp) {
    int i = blockIdx.x * 256 + threadIdx.x;
    if (i >= N_NODES * DIM / 4) return;
    int row = i >> 5;
    int k0 = (i & 31) * 4;
    float nv = norm[row];
    float4 v = f[i];
    uint2 a; a.x = pack2(v.x, v.y); a.y = pack2(v.z, v.w);
    uint2 b; b.x = pack2(v.x * nv, v.y * nv); b.y = pack2(v.z * nv, v.w * nv);
    *(uint2*)(fb + tiled_off(row, k0) / 2) = a;
    fp[i] = b;
}

// ------- SpMM: 4 nodes/wave (16 lanes x 8 bf16), 8/4/2/1 ladder -------
// gather source row-major; hout in tiled layout; preout (optional) row-major
__device__ __forceinline__ void acc8(float* a, uint4 r) {
    a[0] += __builtin_bit_cast(float, r.x << 16);
    a[1] += __builtin_bit_cast(float, r.x & 0xffff0000u);
    a[2] += __builtin_bit_cast(float, r.y << 16);
    a[3] += __builtin_bit_cast(float, r.y & 0xffff0000u);
    a[4] += __builtin_bit_cast(float, r.z << 16);
    a[5] += __builtin_bit_cast(float, r.z & 0xffff0000u);
    a[6] += __builtin_bit_cast(float, r.w << 16);
    a[7] += __builtin_bit_cast(float, r.w & 0xffff0000u);
}

__global__ void k_spmm(const uint4* __restrict__ in, const float* __restrict__ norm,
                       const int* __restrict__ rowstart, const int* __restrict__ esrc,
                       uint4* __restrict__ hout, uint4* __restrict__ preout, int wpre) {
    int v = blockIdx.x * 16 + (threadIdx.x >> 4);
    int l = threadIdx.x & 15;
    if (v >= N_NODES) return;
    int beg = rowstart[v], end = rowstart[v + 1];
    float a[8] = {0.f, 0.f, 0.f, 0.f, 0.f, 0.f, 0.f, 0.f};
    int t = beg;
    for (; t + 7 < end; t += 8) {
        int u0 = esrc[t],     u1 = esrc[t + 1], u2 = esrc[t + 2], u3 = esrc[t + 3];
        int u4 = esrc[t + 4], u5 = esrc[t + 5], u6 = esrc[t + 6], u7 = esrc[t + 7];
        uint4 r0 = in[(size_t)u0 * 16 + l];
        uint4 r1 = in[(size_t)u1 * 16 + l];
        uint4 r2 = in[(size_t)u2 * 16 + l];
        uint4 r3 = in[(size_t)u3 * 16 + l];
        uint4 r4 = in[(size_t)u4 * 16 + l];
        uint4 r5 = in[(size_t)u5 * 16 + l];
        uint4 r6 = in[(size_t)u6 * 16 + l];
        uint4 r7 = in[(size_t)u7 * 16 + l];
        acc8(a, r0); acc8(a, r1); acc8(a, r2); acc8(a, r3);
        acc8(a, r4); acc8(a, r5); acc8(a, r6); acc8(a, r7);
    }
    if (t + 3 < end) {
        int u0 = esrc[t], u1 = esrc[t + 1], u2 = esrc[t + 2], u3 = esrc[t + 3];
        uint4 r0 = in[(size_t)u0 * 16 + l];
        uint4 r1 = in[(size_t)u1 * 16 + l];
        uint4 r2 = in[(size_t)u2 * 16 + l];
        uint4 r3 = in[(size_t)u3 * 16 + l];
        acc8(a, r0); acc8(a, r1); acc8(a, r2); acc8(a, r3);
        t += 4;
    }
    if (t + 1 < end) {
        int u0 = esrc[t], u1 = esrc[t + 1];
        uint4 r0 = in[(size_t)u0 * 16 + l];
        uint4 r1 = in[(size_t)u1 * 16 + l];
        acc8(a, r0); acc8(a, r1);
        t += 2;
    }
    if (t < end) {
        uint4 r = in[(size_t)esrc[t] * 16 + l];
        acc8(a, r);
    }
    float nv = norm[v];
    uint4 o;
    o.x = pack2(a[0] * nv, a[1] * nv); o.y = pack2(a[2] * nv, a[3] * nv);
    o.z = pack2(a[4] * nv, a[5] * nv); o.w = pack2(a[6] * nv, a[7] * nv);
    // tiled store: cols l*8..l*8+7 of row v
    size_t tix = (size_t)(v >> 4) * 256 + (size_t)(l >> 2) * 64
               + (size_t)(l & 3) * 16 + (v & 15);
    hout[tix] = o;
    if (wpre) {
        float n2 = nv * nv;
        uint4 p;
        p.x = pack2(a[0] * n2, a[1] * n2); p.y = pack2(a[2] * n2, a[3] * n2);
        p.z = pack2(a[4] * n2, a[5] * n2); p.w = pack2(a[6] * n2, a[7] * n2);
        preout[(size_t)v * 16 + l] = p;
    }
}

// ------- fused tri-GEMM: contiguous-1KB global_load_lds from tiled A arrays -------
// slice s = g*16 + rt*4 + ks; global source = base + ((r0>>4)+rt)*2048 + ks*512
// + lane*8 (fully lane-linear -> one sequential 1KB fetch per DMA). LDS layout and
// read phase identical to R5 (proven conflict-free).
#define RT 64

typedef const __attribute__((address_space(1))) unsigned int* gp1_t;
typedef __attribute__((address_space(3))) unsigned int* lp3_t;

__global__ __launch_bounds__(512, 4) void k_gemm_fused(
    const short* __restrict__ hB, const short* __restrict__ fB,
    const short* __restrict__ h1B, const short* __restrict__ Wb,
    const float* __restrict__ bias, const float* __restrict__ snorm,
    float* __restrict__ out) {
    __shared__ short Ts[48 * 512];   // 48 KB

    const int r0 = blockIdx.x * RT;
    const int tid = threadIdx.x;
    const int lane = tid & 63;
    const int wv = tid >> 6;         // 0..7: wave owns one 16-col output tile
    const int m = lane & 15;
    const int quad = lane >> 4;

    // stage A tiles: wave wv issues slices wv*6 .. wv*6+5 (each one contiguous 1KB)
#pragma unroll
    for (int i = 0; i < 6; ++i) {
        int s = wv * 6 + i;
        int g = s >> 4, rt = (s >> 2) & 3, ks = s & 3;
        const short* base = (g == 0) ? hB : (g == 1) ? fB : h1B;
        const short* gp = base + (size_t)((r0 >> 4) + rt) * 2048 + ks * 512 + lane * 8;
        __builtin_amdgcn_global_load_lds((gp1_t)(const void*)gp,
                                         (lp3_t)(void*)&Ts[s * 512], 16, 0, 0);
    }
    __syncthreads();

    float4v acc[3][4];
    const float4v zero = {0.f, 0.f, 0.f, 0.f};
#pragma unroll
    for (int g = 0; g < 3; ++g)
#pragma unroll
        for (int rt = 0; rt < 4; ++rt) acc[g][rt] = zero;

    const short* wp = Wb + (size_t)(wv * 16 + m) * DIM + quad * 8;
#pragma unroll
    for (int ks = 0; ks < 4; ++ks) {
        const int ko = ks * 32;
        short8 b0 = *(const short8*)(wp + ko);
        short8 b1 = *(const short8*)(wp + ko + DIM * DIM);
        short8 b2 = *(const short8*)(wp + ko + 2 * DIM * DIM);
        short8 b3 = *(const short8*)(wp + ko + 3 * DIM * DIM);
        short8 b4 = *(const short8*)(wp + ko + 4 * DIM * DIM);
        short8 b5 = *(const short8*)(wp + ko + 5 * DIM * DIM);
#pragma unroll
        for (int rt = 0; rt < 4; ++rt) {
            const short* ap = &Ts[(rt * 4 + ks) * 512 + lane * 8];
            short8 x_h = *(const short8*)(ap);
            short8 x_f = *(const short8*)(ap + 16 * 512);
            short8 x_1 = *(const short8*)(ap + 32 * 512);
            acc[0][rt] = __builtin_amdgcn_mfma_f32_16x16x32_bf16(x_h, b0, acc[0][rt], 0, 0, 0);
            acc[0][rt] = __builtin_amdgcn_mfma_f32_16x16x32_bf16(x_f, b1, acc[0][rt], 0, 0, 0);
            acc[1][rt] = __builtin_amdgcn_mfma_f32_16x16x32_bf16(x_h, b2, acc[1][rt], 0, 0, 0);
            acc[1][rt] = __builtin_amdgcn_mfma_f32_16x16x32_bf16(x_f, b3, acc[1][rt], 0, 0, 0);
            acc[2][rt] = __builtin_amdgcn_mfma_f32_16x16x32_bf16(x_1, b4, acc[2][rt], 0, 0, 0);
            acc[2][rt] = __builtin_amdgcn_mfma_f32_16x16x32_bf16(x_f, b5, acc[2][rt], 0, 0, 0);
        }
    }

    // epilogue: sequential mutual gating + bias + graph-norm + relu
    const int col = wv * 16 + m;
    const float bc = bias[col];
#pragma unroll
    for (int rt = 0; rt < 4; ++rt) {
#pragma unroll
        for (int r = 0; r < 4; ++r) {
            int row = r0 + rt * 16 + quad * 4 + r;
            if (row < N_NODES) {
                float sn = snorm[row];
                float o0 = acc[0][rt][r], o1 = acc[1][rt][r], o2 = acc[2][rt][r];
                float g0 = o0 * sigm(o1 + o2);
                float g1 = o1 * sigm(g0 + o2);
                float g2 = o2 * sigm(g0 + g1);
                float vv = (g0 + g1 + g2 + bc) * sn;
                out[(size_t)row * DIM + col] = fmaxf(vv, 0.f);
            }
        }
    }
}

extern "C" void kernel_launch(void* const* d_in, const int* in_sizes, int n_in,
                              void* d_out, int out_size, void* d_ws, size_t ws_size,
                              hipStream_t stream) {
    const float* feature = (const float*)d_in[0];
    const float* snorm   = (const float*)d_in[1];
    const int*   src     = (const int*)d_in[2];
    const int*   dst     = (const int*)d_in[3];
    const float* W_low   = (const float*)d_in[4];
    const float* W_high  = (const float*)d_in[5];
    const float* W_mid   = (const float*)d_in[6];
    const float* gl      = (const float*)d_in[7];
    const float* gh      = (const float*)d_in[8];
    const float* gm      = (const float*)d_in[9];
    const float* bias    = (const float*)d_in[10];
    float* out = (float*)d_out;

    char* w = (char*)d_ws;
    auto alloc = [&](size_t bytes) {
        char* p = w;
        w += (bytes + 255) & ~(size_t)255;
        return p;
    };
    const size_t tiledBytes = (size_t)RBLK * 2048 * 2;   // padded tiled bf16 array
    float* norm   = (float*)alloc((size_t)N_NODES * 4);
    int* deg      = (int*)alloc((size_t)2 * N_NODES * 4);
    int* cnt      = deg + N_NODES;
    int* rowstart = (int*)alloc((size_t)(N_NODES + 1) * 4);
    int* bsums    = (int*)alloc(64 * 4);
    int* esrc     = (int*)alloc((size_t)N_EDGES * 4);
    short* Wb     = (short*)alloc((size_t)6 * DIM * DIM * 2);
    short* fb     = (short*)alloc(tiledBytes);                    // tiled
    short* fp     = (short*)alloc((size_t)N_NODES * DIM * 2);     // row-major
    short* h      = (short*)alloc(tiledBytes);                    // tiled
    short* hp     = (short*)alloc((size_t)N_NODES * DIM * 2);     // row-major
    short* h1     = (short*)alloc(tiledBytes);                    // tiled

    hipMemsetAsync(deg, 0, (size_t)2 * N_NODES * 4, stream);
    k_deg<<<(N_EDGES + 255) / 256, 256, 0, stream>>>(dst, deg);
    int nchunks = (N_NODES + 1023) / 1024;  // 49
    k_scan1<<<nchunks, 256, 0, stream>>>(deg, rowstart, bsums, norm);
    k_scan2<<<1, 64, 0, stream>>>(bsums, nchunks);
    k_scan3<<<(N_NODES + 255) / 256, 256, 0, stream>>>(bsums, rowstart);
    k_fill<<<(N_EDGES + 255) / 256, 256, 0, stream>>>(src, dst, rowstart, cnt, esrc);
    k_wconv<<<dim3(16, 6), 256, 0, stream>>>(W_low, W_high, W_mid, gl, gh, gm,
                                             (unsigned int*)Wb);
    k_prescale<<<(N_NODES * DIM / 4 + 255) / 256, 256, 0, stream>>>(
        (const float4*)feature, norm, (unsigned int*)fb, (uint2*)fp);

    int spmm_blocks = (N_NODES + 15) / 16;
    k_spmm<<<spmm_blocks, 256, 0, stream>>>((const uint4*)fp, norm, rowstart, esrc,
                                            (uint4*)h, (uint4*)hp, 1);
    k_spmm<<<spmm_blocks, 256, 0, stream>>>((const uint4*)hp, norm, rowstart, esrc,
                                            (uint4*)h1, (uint4*)hp, 0);

    k_gemm_fused<<<(N_NODES + RT - 1) / RT, 512, 0, stream>>>(
        h, fb, h1, Wb, bias, snorm, out);
}

// Round 7
// 252.927 us; speedup vs baseline: 1.1415x; 1.0112x over previous
//
#include <hip/hip_runtime.h>
#include <hip/hip_bf16.h>
#include <math.h>

#define N_NODES 50000
#define N_EDGES 600000
#define DIM 128
#define KGAM 8
#define EPSV 1e-9f
#define RBLK 3128    // padded 16-row blocks in tiled A arrays (50048 rows)
#define NTILES 1564  // 32-row GEMM tiles
#define GGRID 512    // persistent-ish grid

typedef __attribute__((ext_vector_type(8))) short short8;
typedef __attribute__((ext_vector_type(4))) float float4v;

__device__ __forceinline__ short f2bf(float f) {
    return (short)__builtin_bit_cast(unsigned short, __float2bfloat16(f));
}
__device__ __forceinline__ unsigned int pack2(float a, float b) {
    return (unsigned int)(unsigned short)f2bf(a) | ((unsigned int)(unsigned short)f2bf(b) << 16);
}
__device__ __forceinline__ float sigm(float x) { return 1.f / (1.f + __expf(-x)); }

// ---------------- CSR build ----------------
__global__ void k_deg(const int* __restrict__ dst, int* __restrict__ deg) {
    int e = blockIdx.x * blockDim.x + threadIdx.x;
    if (e < N_EDGES) atomicAdd(&deg[dst[e]], 1);
}

__global__ void k_scan1(const int* __restrict__ deg, int* __restrict__ rowstart,
                        int* __restrict__ bsums, float* __restrict__ norm) {
    __shared__ int s[256];
    int tid = threadIdx.x;
    int i0 = blockIdx.x * 1024 + tid * 4;
    int v[4]; int sum = 0;
#pragma unroll
    for (int c = 0; c < 4; ++c) {
        int i = i0 + c;
        int d = (i < N_NODES) ? deg[i] : 0;
        v[c] = d; sum += d;
    }
    s[tid] = sum; __syncthreads();
#pragma unroll
    for (int off = 1; off < 256; off <<= 1) {
        int t = (tid >= off) ? s[tid - off] : 0;
        __syncthreads();
        s[tid] += t;
        __syncthreads();
    }
    if (tid == 255) bsums[blockIdx.x] = s[255];
    int run = s[tid] - sum;
#pragma unroll
    for (int c = 0; c < 4; ++c) {
        int i = i0 + c;
        if (i < N_NODES) {
            rowstart[i] = run;
            norm[i] = rsqrtf((float)(v[c] < 1 ? 1 : v[c]));
        }
        run += v[c];
    }
}

__global__ void k_scan2(int* __restrict__ bsums, int nb) {
    __shared__ int s[64];
    int tid = threadIdx.x;
    int v = (tid < nb) ? bsums[tid] : 0;
    s[tid] = v; __syncthreads();
#pragma unroll
    for (int off = 1; off < 64; off <<= 1) {
        int t = (tid >= off) ? s[tid - off] : 0;
        __syncthreads();
        s[tid] += t;
        __syncthreads();
    }
    if (tid < nb) bsums[tid] = s[tid] - v;
}

__global__ void k_scan3(const int* __restrict__ bsums, int* __restrict__ rowstart) {
    int i = blockIdx.x * blockDim.x + threadIdx.x;
    if (i < N_NODES) rowstart[i] += bsums[i >> 10];
    if (i == 0) rowstart[N_NODES] = N_EDGES;
}

__global__ void k_fill(const int* __restrict__ src, const int* __restrict__ dst,
                       const int* __restrict__ rowstart, int* __restrict__ cnt,
                       int* __restrict__ esrc) {
    int e = blockIdx.x * blockDim.x + threadIdx.x;
    if (e < N_EDGES) {
        int d = dst[e];
        int slot = rowstart[d] + atomicAdd(&cnt[d], 1);
        esrc[slot] = src[e];
    }
}

// ------------- weights: 6 coefficient-folded bf16 matrices (coeffs inlined) -------
__global__ void k_wconv(const float* __restrict__ W0, const float* __restrict__ W1,
                        const float* __restrict__ W2, const float* __restrict__ gl,
                        const float* __restrict__ gh, const float* __restrict__ gm,
                        unsigned int* __restrict__ Wb) {
    int g = blockIdx.y;
    float a0 = 0, b0 = 0, a1 = 0, b1 = 0, sg = 0, m2 = 0;
#pragma unroll
    for (int k = 0; k < KGAM; ++k) {
        float al = EPSV + (float)k * (1.f - 2.f * EPSV) / (KGAM - 1);
        float md = EPSV + (float)k * (1.f - EPSV) / (KGAM - 1);
        float l = fmaxf(gl[k], 0.f), h = fmaxf(gh[k], 0.f), m = fmaxf(gm[k], 0.f);
        a0 += al * l;  b0 += (1.f - al) * l;
        a1 += -al * h; b1 += (1.f - al) * h;
        sg += m;       m2 += md * m;
    }
    float cc[6] = {a0, b0, a1, b1, sg, -m2};
    float c = cc[g];
    const float* Ws = (g < 2) ? W0 : (g < 4) ? W1 : W2;
    int i = (blockIdx.x * 256 + threadIdx.x) * 4;
    if (i < DIM * DIM) {
        float4 v = *(const float4*)(Ws + i);
        uint2 o; o.x = pack2(c * v.x, c * v.y); o.y = pack2(c * v.z, c * v.w);
        *(uint2*)(Wb + (g * DIM * DIM + i) / 2) = o;
    }
}

// tiled A-layout short-offset for (row, k)
__device__ __forceinline__ size_t tiled_off(int row, int k) {
    return (size_t)(row >> 4) * 2048 + ((k >> 5) << 9) + (((k >> 3) & 3) << 7)
         + ((row & 15) << 3) + (k & 7);
}

// -------- prescale: fb = bf16(feature) [tiled], fp = bf16(feature*norm) [row-major]
__global__ void k_prescale(const float4* __restrict__ f, const float* __restrict__ norm,
                           unsigned int* __restrict__ fb, uint2* __restrict__ fp) {
    int i = blockIdx.x * 256 + threadIdx.x;
    if (i >= N_NODES * DIM / 4) return;
    int row = i >> 5;
    int k0 = (i & 31) * 4;
    float nv = norm[row];
    float4 v = f[i];
    uint2 a; a.x = pack2(v.x, v.y); a.y = pack2(v.z, v.w);
    uint2 b; b.x = pack2(v.x * nv, v.y * nv); b.y = pack2(v.z * nv, v.w * nv);
    *(uint2*)(fb + tiled_off(row, k0) / 2) = a;
    fp[i] = b;
}

// ------- SpMM: 4 nodes/wave (16 lanes x 8 bf16), 8/4/2/1 ladder -------
__device__ __forceinline__ void acc8(float* a, uint4 r) {
    a[0] += __builtin_bit_cast(float, r.x << 16);
    a[1] += __builtin_bit_cast(float, r.x & 0xffff0000u);
    a[2] += __builtin_bit_cast(float, r.y << 16);
    a[3] += __builtin_bit_cast(float, r.y & 0xffff0000u);
    a[4] += __builtin_bit_cast(float, r.z << 16);
    a[5] += __builtin_bit_cast(float, r.z & 0xffff0000u);
    a[6] += __builtin_bit_cast(float, r.w << 16);
    a[7] += __builtin_bit_cast(float, r.w & 0xffff0000u);
}

__global__ void k_spmm(const uint4* __restrict__ in, const float* __restrict__ norm,
                       const int* __restrict__ rowstart, const int* __restrict__ esrc,
                       uint4* __restrict__ hout, uint4* __restrict__ preout, int wpre) {
    int v = blockIdx.x * 16 + (threadIdx.x >> 4);
    int l = threadIdx.x & 15;
    if (v >= N_NODES) return;
    int beg = rowstart[v], end = rowstart[v + 1];
    float a[8] = {0.f, 0.f, 0.f, 0.f, 0.f, 0.f, 0.f, 0.f};
    int t = beg;
    for (; t + 7 < end; t += 8) {
        int u0 = esrc[t],     u1 = esrc[t + 1], u2 = esrc[t + 2], u3 = esrc[t + 3];
        int u4 = esrc[t + 4], u5 = esrc[t + 5], u6 = esrc[t + 6], u7 = esrc[t + 7];
        uint4 r0 = in[(size_t)u0 * 16 + l];
        uint4 r1 = in[(size_t)u1 * 16 + l];
        uint4 r2 = in[(size_t)u2 * 16 + l];
        uint4 r3 = in[(size_t)u3 * 16 + l];
        uint4 r4 = in[(size_t)u4 * 16 + l];
        uint4 r5 = in[(size_t)u5 * 16 + l];
        uint4 r6 = in[(size_t)u6 * 16 + l];
        uint4 r7 = in[(size_t)u7 * 16 + l];
        acc8(a, r0); acc8(a, r1); acc8(a, r2); acc8(a, r3);
        acc8(a, r4); acc8(a, r5); acc8(a, r6); acc8(a, r7);
    }
    if (t + 3 < end) {
        int u0 = esrc[t], u1 = esrc[t + 1], u2 = esrc[t + 2], u3 = esrc[t + 3];
        uint4 r0 = in[(size_t)u0 * 16 + l];
        uint4 r1 = in[(size_t)u1 * 16 + l];
        uint4 r2 = in[(size_t)u2 * 16 + l];
        uint4 r3 = in[(size_t)u3 * 16 + l];
        acc8(a, r0); acc8(a, r1); acc8(a, r2); acc8(a, r3);
        t += 4;
    }
    if (t + 1 < end) {
        int u0 = esrc[t], u1 = esrc[t + 1];
        uint4 r0 = in[(size_t)u0 * 16 + l];
        uint4 r1 = in[(size_t)u1 * 16 + l];
        acc8(a, r0); acc8(a, r1);
        t += 2;
    }
    if (t < end) {
        uint4 r = in[(size_t)esrc[t] * 16 + l];
        acc8(a, r);
    }
    float nv = norm[v];
    uint4 o;
    o.x = pack2(a[0] * nv, a[1] * nv); o.y = pack2(a[2] * nv, a[3] * nv);
    o.z = pack2(a[4] * nv, a[5] * nv); o.w = pack2(a[6] * nv, a[7] * nv);
    size_t tix = (size_t)(v >> 4) * 256 + (size_t)(l >> 2) * 64
               + (size_t)(l & 3) * 16 + (v & 15);
    hout[tix] = o;
    if (wpre) {
        float n2 = nv * nv;
        uint4 p;
        p.x = pack2(a[0] * n2, a[1] * n2); p.y = pack2(a[2] * n2, a[3] * n2);
        p.z = pack2(a[4] * n2, a[5] * n2); p.w = pack2(a[6] * n2, a[7] * n2);
        preout[(size_t)v * 16 + l] = p;
    }
}

// ------- fused tri-GEMM: persistent grid, double-buffered LDS pipeline -------
// 32-row tiles; wave wv owns col-tile ct=wv. Slice (g,rb,ks) = g*8+rb*4+ks, 1KB
// contiguous in tiled A array. Barrier at iter i+1 drains DMA(i+1) issued before
// compute(i) -> staging latency hidden behind MFMA/epilogue.
// A: lane holds A[m=lane&15][k=quad*8+j]; B: W[n=lane&15][k=quad*8+j];
// C/D: col=lane&15, row=quad*4+reg (verified R2-R6)
typedef const __attribute__((address_space(1))) unsigned int* gp1_t;
typedef __attribute__((address_space(3))) unsigned int* lp3_t;

__global__ __launch_bounds__(512, 2) void k_gemm_fused(
    const short* __restrict__ hB, const short* __restrict__ fB,
    const short* __restrict__ h1B, const short* __restrict__ Wb,
    const float* __restrict__ bias, const float* __restrict__ snorm,
    float* __restrict__ out) {
    __shared__ short Ts[2][24 * 512];   // 2 x 24KB

    const int tid = threadIdx.x;
    const int lane = tid & 63;
    const int wv = tid >> 6;     // = ct
    const int m = lane & 15;
    const int quad = lane >> 4;

    const int col = wv * 16 + m;
    const float bc = bias[col];
    const short* wp = Wb + (size_t)col * DIM + quad * 8;

    // prologue DMA for first tile
    int t0 = blockIdx.x;
    {
#pragma unroll
        for (int i = 0; i < 3; ++i) {
            int s = wv * 3 + i;                  // 0..23
            int g = s >> 3, rb = (s >> 2) & 1, ks = s & 3;
            const short* base = (g == 0) ? hB : (g == 1) ? fB : h1B;
            const short* gp = base + (size_t)(t0 * 2 + rb) * 2048 + ks * 512 + lane * 8;
            __builtin_amdgcn_global_load_lds((gp1_t)(const void*)gp,
                                             (lp3_t)(void*)&Ts[0][s * 512], 16, 0, 0);
        }
    }

    int buf = 0;
    for (int t = t0; t < NTILES; t += GGRID) {
        __syncthreads();   // drains DMA(buf); all waves done reading buf^1

        int tn = t + GGRID;
        if (tn < NTILES) {
#pragma unroll
            for (int i = 0; i < 3; ++i) {
                int s = wv * 3 + i;
                int g = s >> 3, rb = (s >> 2) & 1, ks = s & 3;
                const short* base = (g == 0) ? hB : (g == 1) ? fB : h1B;
                const short* gp = base + (size_t)(tn * 2 + rb) * 2048 + ks * 512 + lane * 8;
                __builtin_amdgcn_global_load_lds((gp1_t)(const void*)gp,
                                                 (lp3_t)(void*)&Ts[buf ^ 1][s * 512], 16, 0, 0);
            }
        }

        float4v acc[3][2];
        const float4v zero = {0.f, 0.f, 0.f, 0.f};
#pragma unroll
        for (int g = 0; g < 3; ++g) {
            acc[g][0] = zero; acc[g][1] = zero;
        }

#pragma unroll
        for (int ks = 0; ks < 4; ++ks) {
            const short* wk = wp + ks * 32;
            short8 b0 = *(const short8*)(wk);
            short8 b1 = *(const short8*)(wk + DIM * DIM);
            short8 b2 = *(const short8*)(wk + 2 * DIM * DIM);
            short8 b3 = *(const short8*)(wk + 3 * DIM * DIM);
            short8 b4 = *(const short8*)(wk + 4 * DIM * DIM);
            short8 b5 = *(const short8*)(wk + 5 * DIM * DIM);
#pragma unroll
            for (int rb = 0; rb < 2; ++rb) {
                const short* ap = &Ts[buf][(rb * 4 + ks) * 512 + lane * 8];
                short8 x_h = *(const short8*)(ap);
                short8 x_f = *(const short8*)(ap + 8 * 512);
                short8 x_1 = *(const short8*)(ap + 16 * 512);
                acc[0][rb] = __builtin_amdgcn_mfma_f32_16x16x32_bf16(x_h, b0, acc[0][rb], 0, 0, 0);
                acc[0][rb] = __builtin_amdgcn_mfma_f32_16x16x32_bf16(x_f, b1, acc[0][rb], 0, 0, 0);
                acc[1][rb] = __builtin_amdgcn_mfma_f32_16x16x32_bf16(x_h, b2, acc[1][rb], 0, 0, 0);
                acc[1][rb] = __builtin_amdgcn_mfma_f32_16x16x32_bf16(x_f, b3, acc[1][rb], 0, 0, 0);
                acc[2][rb] = __builtin_amdgcn_mfma_f32_16x16x32_bf16(x_1, b4, acc[2][rb], 0, 0, 0);
                acc[2][rb] = __builtin_amdgcn_mfma_f32_16x16x32_bf16(x_f, b5, acc[2][rb], 0, 0, 0);
            }
        }

        // epilogue: sequential mutual gating + bias + graph-norm + relu
#pragma unroll
        for (int rb = 0; rb < 2; ++rb) {
#pragma unroll
            for (int r = 0; r < 4; ++r) {
                int row = t * 32 + rb * 16 + quad * 4 + r;
                if (row < N_NODES) {
                    float sn = snorm[row];
                    float o0 = acc[0][rb][r], o1 = acc[1][rb][r], o2 = acc[2][rb][r];
                    float g0 = o0 * sigm(o1 + o2);
                    float g1 = o1 * sigm(g0 + o2);
                    float g2 = o2 * sigm(g0 + g1);
                    float vv = (g0 + g1 + g2 + bc) * sn;
                    out[(size_t)row * DIM + col] = fmaxf(vv, 0.f);
                }
            }
        }
        buf ^= 1;
    }
}

extern "C" void kernel_launch(void* const* d_in, const int* in_sizes, int n_in,
                              void* d_out, int out_size, void* d_ws, size_t ws_size,
                              hipStream_t stream) {
    const float* feature = (const float*)d_in[0];
    const float* snorm   = (const float*)d_in[1];
    const int*   src     = (const int*)d_in[2];
    const int*   dst     = (const int*)d_in[3];
    const float* W_low   = (const float*)d_in[4];
    const float* W_high  = (const float*)d_in[5];
    const float* W_mid   = (const float*)d_in[6];
    const float* gl      = (const float*)d_in[7];
    const float* gh      = (const float*)d_in[8];
    const float* gm      = (const float*)d_in[9];
    const float* bias    = (const float*)d_in[10];
    float* out = (float*)d_out;

    char* w = (char*)d_ws;
    auto alloc = [&](size_t bytes) {
        char* p = w;
        w += (bytes + 255) & ~(size_t)255;
        return p;
    };
    const size_t tiledBytes = (size_t)RBLK * 2048 * 2;
    float* norm   = (float*)alloc((size_t)N_NODES * 4);
    int* deg      = (int*)alloc((size_t)2 * N_NODES * 4);
    int* cnt      = deg + N_NODES;
    int* rowstart = (int*)alloc((size_t)(N_NODES + 1) * 4);
    int* bsums    = (int*)alloc(64 * 4);
    int* esrc     = (int*)alloc((size_t)N_EDGES * 4);
    short* Wb     = (short*)alloc((size_t)6 * DIM * DIM * 2);
    short* fb     = (short*)alloc(tiledBytes);                    // tiled
    short* fp     = (short*)alloc((size_t)N_NODES * DIM * 2);     // row-major
    short* h      = (short*)alloc(tiledBytes);                    // tiled
    short* hp     = (short*)alloc((size_t)N_NODES * DIM * 2);     // row-major
    short* h1     = (short*)alloc(tiledBytes);                    // tiled

    hipMemsetAsync(deg, 0, (size_t)2 * N_NODES * 4, stream);
    k_deg<<<(N_EDGES + 255) / 256, 256, 0, stream>>>(dst, deg);
    int nchunks = (N_NODES + 1023) / 1024;  // 49
    k_scan1<<<nchunks, 256, 0, stream>>>(deg, rowstart, bsums, norm);
    k_scan2<<<1, 64, 0, stream>>>(bsums, nchunks);
    k_scan3<<<(N_NODES + 255) / 256, 256, 0, stream>>>(bsums, rowstart);
    k_fill<<<(N_EDGES + 255) / 256, 256, 0, stream>>>(src, dst, rowstart, cnt, esrc);
    k_wconv<<<dim3(16, 6), 256, 0, stream>>>(W_low, W_high, W_mid, gl, gh, gm,
                                             (unsigned int*)Wb);
    k_prescale<<<(N_NODES * DIM / 4 + 255) / 256, 256, 0, stream>>>(
        (const float4*)feature, norm, (unsigned int*)fb, (uint2*)fp);

    int spmm_blocks = (N_NODES + 15) / 16;
    k_spmm<<<spmm_blocks, 256, 0, stream>>>((const uint4*)fp, norm, rowstart, esrc,
                                            (uint4*)h, (uint4*)hp, 1);
    k_spmm<<<spmm_blocks, 256, 0, stream>>>((const uint4*)hp, norm, rowstart, esrc,
                                            (uint4*)h1, (uint4*)hp, 0);

    k_gemm_fused<<<GGRID, 512, 0, stream>>>(h, fb, h1, Wb, bias, snorm, out);
}